// Round 2
// baseline (281.110 us; speedup 1.0000x reference)
//
#include <hip/hip_runtime.h>
#include <hip/hip_bf16.h>
#include <math.h>

// 2-bit-weight conv2d (64,128,56,56)x(256,128,3,3) s1 p1 + BN(inference)
// + hardtanh + 2-bit activation quantize. f32 in/out.
//
// quantize(w) = round(clip(w,-1,1)*2)/2; weights are N(0,1)*0.05, so a
// nonzero quantized weight is a 5-sigma event (expected nnz ~ 0.17 of
// 294,912). Verified round 1: absmax 0.0 with sparse evaluation. The kernel
// is therefore a write-roofline problem: 205 MB of stores ~= 31 us at the
// measured 6.6 TB/s fill ceiling.
//
// Round-2 structure: ONE kernel, one block per (b,co) output plane.
//   - block computes BN scale/shift for its channel (thread 0 -> LDS)
//   - block scans its channel's 1152 weights into an LDS nonzero list
//     (max possible cnt == 1152 == array size; no overflow, no global atomics)
//   - cnt==0 (the real data): whole plane is the constant quantize(shift)
//     -> pure float4 fill, same access pattern as fillBufferAligned
//   - cnt>0: sparse conv fallback per element (kept for correctness)
//
// Numerics mirror the reference op-for-op (outputs are exact multiples of
// 0.5, threshold 1e-2 -> one mis-rounding fails):
//   jnp.round == round-half-even -> rintf;  y*scale+shift as two rounded
//   ops (no fma) -> __fmul_rn/__fadd_rn;  rsqrt via double 1/sqrt rounded
//   once to f32;  *2 and *0.5 exact.

__global__ void __launch_bounds__(256)
fused_all(const float* __restrict__ x,
          const float* __restrict__ w,
          const float* __restrict__ gamma,
          const float* __restrict__ beta,
          const float* __restrict__ rmean,
          const float* __restrict__ rvar,
          float* __restrict__ out) {
    __shared__ int   s_cnt;
    __shared__ float s_scale, s_shift;
    __shared__ int   s_idx[1152];
    __shared__ float s_q[1152];

    const int bid = blockIdx.x;          // 0 .. 16383
    const int co  = bid >> 6;            // consecutive blocks share a channel
    const int b   = bid & 63;            //   -> weight slice stays hot in L2
    const int tid = threadIdx.x;

    if (tid == 0) {
        s_cnt = 0;
        float s   = rvar[co] + 1e-5f;                  // f32 add, like reference
        float inv = (float)(1.0 / sqrt((double)s));    // correctly-rounded rsqrt
        float g   = gamma[co];
        s_scale = __fmul_rn(g, inv);
        // shift = beta - (running_mean * gamma) * inv   (left-assoc)
        s_shift = __fsub_rn(beta[co], __fmul_rn(__fmul_rn(rmean[co], g), inv));
    }
    __syncthreads();

    // scan this output channel's 1152 weights for nonzero quantized values
    const float* wc = w + co * 1152;
    for (int j = tid; j < 1152; j += 256) {
        float wv = wc[j];
        float c  = fminf(fmaxf(wv, -1.0f), 1.0f);
        float q  = rintf(c * 2.0f) * 0.5f;             // exact pow2 scaling
        if (q != 0.0f) {
            int slot = atomicAdd(&s_cnt, 1);           // LDS atomic, ~never taken
            s_idx[slot] = j;
            s_q[slot]   = q;
        }
    }
    __syncthreads();

    const int   cnt = s_cnt;
    const float sc  = s_scale;
    const float sh  = s_shift;
    float4* out4 = (float4*)(out + (((size_t)b << 8) + co) * 3136);

    if (cnt == 0) {
        // conv output is exactly 0.0f everywhere in this plane
        float y = __fadd_rn(__fmul_rn(0.0f, sc), sh);
        y = fminf(fmaxf(y, -1.0f), 1.0f);
        float qv = rintf(y * 2.0f) * 0.5f;
        float4 o = {qv, qv, qv, qv};
        #pragma unroll
        for (int i = tid; i < 784; i += 256) out4[i] = o;   // pure fill
        return;
    }

    // ---- sparse-conv fallback (correct for any nnz up to full density) ----
    const float* xb = x + (size_t)b * 128 * 3136;
    for (int i = tid; i < 784; i += 256) {
        int flat = i * 4;                  // 56 % 4 == 0: 4 positions, one h row
        int h  = flat / 56;
        int w0 = flat - h * 56;

        float acc0 = 0.0f, acc1 = 0.0f, acc2 = 0.0f, acc3 = 0.0f;
        for (int e = 0; e < cnt; ++e) {
            int   idx = s_idx[e];
            float q   = s_q[e];
            int ci = idx / 9;
            int r9 = idx - ci * 9;
            int kh = r9 / 3;
            int kw = r9 - kh * 3;
            int hh = h + kh - 1;
            if (hh < 0 || hh >= 56) continue;
            const float* xrow = xb + (ci * 56 + hh) * 56;
            int wb = w0 + kw - 1;              // in [-1, 53]
            if (wb >= 0)      acc0 += q * xrow[wb];
            /* wb+1 >= 0 */   acc1 += q * xrow[wb + 1];
            /* wb+2 >= 0 */   if (wb + 2 < 56) acc2 += q * xrow[wb + 2];
            if (wb + 3 < 56)  acc3 += q * xrow[wb + 3];
        }

        float4 o;
        {
            float y = __fadd_rn(__fmul_rn(acc0, sc), sh);
            y = fminf(fmaxf(y, -1.0f), 1.0f);
            o.x = rintf(y * 2.0f) * 0.5f;
        }
        {
            float y = __fadd_rn(__fmul_rn(acc1, sc), sh);
            y = fminf(fmaxf(y, -1.0f), 1.0f);
            o.y = rintf(y * 2.0f) * 0.5f;
        }
        {
            float y = __fadd_rn(__fmul_rn(acc2, sc), sh);
            y = fminf(fmaxf(y, -1.0f), 1.0f);
            o.z = rintf(y * 2.0f) * 0.5f;
        }
        {
            float y = __fadd_rn(__fmul_rn(acc3, sc), sh);
            y = fminf(fmaxf(y, -1.0f), 1.0f);
            o.w = rintf(y * 2.0f) * 0.5f;
        }
        out4[i] = o;
    }
}

extern "C" void kernel_launch(void* const* d_in, const int* in_sizes, int n_in,
                              void* d_out, int out_size, void* d_ws, size_t ws_size,
                              hipStream_t stream) {
    const float* x     = (const float*)d_in[0];
    const float* w     = (const float*)d_in[1];
    const float* gamma = (const float*)d_in[2];
    const float* beta  = (const float*)d_in[3];
    const float* rmean = (const float*)d_in[4];
    const float* rvar  = (const float*)d_in[5];
    float* out = (float*)d_out;

    // one block per (b, co) output plane: 64 * 256 = 16384 blocks
    fused_all<<<16384, 256, 0, stream>>>(x, w, gamma, beta, rmean, rvar, out);
}

// Round 3
// 260.402 us; speedup vs baseline: 1.0795x; 1.0795x over previous
//
#include <hip/hip_runtime.h>
#include <hip/hip_bf16.h>
#include <math.h>

// 2-bit-weight conv2d (64,128,56,56)x(256,128,3,3) s1 p1 + BN(inference)
// + hardtanh + 2-bit activation quantize. f32 in/out.
//
// quantize(w) = round(clip(w,-1,1)*2)/2; weights are N(0,1)*0.05 -> nonzero
// quantized weight is a 5-sigma event (expected nnz ~ 0.17 of 294,912).
// Verified rounds 1-2: absmax 0.0. The problem is a write-roofline fill:
// 205 MB of stores ~= 31 us at the measured ~6.6 TB/s fill ceiling.
// dur_us is dominated by ~250 us of harness poison fills (822 MB each at
// 122-131 us) that sit inside the timed window; round1->round2 delta was
// chip-speed noise (fills themselves slowed 5%).
//
// Round-3: trim the controllable path.
//   - float4 weight scan (288 loads/block), flag-only in the common path
//   - nnz>0 fallback rebuilds the LDS list then does sparse conv (unchanged
//     logic, verified structure)
//   - fill fully unrolled: 3 unconditional dwordx4 stores + 1 predicated
//   - channel-contiguous block mapping: adjacent blocks write adjacent memory
//
// Numerics mirror the reference op-for-op (outputs are exact multiples of
// 0.5): jnp.round == round-half-even -> rintf; y*scale+shift as two rounded
// ops (no fma) -> __fmul_rn/__fadd_rn; rsqrt via double 1/sqrt rounded once;
// *2 and *0.5 exact.

__global__ void __launch_bounds__(256)
fused_all(const float* __restrict__ x,
          const float* __restrict__ w,
          const float* __restrict__ gamma,
          const float* __restrict__ beta,
          const float* __restrict__ rmean,
          const float* __restrict__ rvar,
          float* __restrict__ out) {
    __shared__ int   s_flag;
    __shared__ int   s_cnt;
    __shared__ float s_scale, s_shift;
    __shared__ int   s_idx[1152];
    __shared__ float s_q[1152];

    const int bid = blockIdx.x;          // 0 .. 16383
    const int co  = bid & 255;           // adjacent blocks -> adjacent planes
    const int b   = bid >> 8;
    const int tid = threadIdx.x;

    if (tid == 0) {
        s_flag = 0;
        float s   = rvar[co] + 1e-5f;                  // f32 add, like reference
        float inv = (float)(1.0 / sqrt((double)s));    // correctly-rounded rsqrt
        float g   = gamma[co];
        s_scale = __fmul_rn(g, inv);
        // shift = beta - (running_mean * gamma) * inv   (left-assoc)
        s_shift = __fsub_rn(beta[co], __fmul_rn(__fmul_rn(rmean[co], g), inv));
    }

    // vectorized scan: does this channel have ANY nonzero quantized weight?
    // 1152 floats = 288 float4; threads 0..255 read j=tid, threads 0..31 also j=tid+256
    const float4* wc4 = (const float4*)(w + co * 1152);
    bool nz = false;
    {
        float4 v = wc4[tid];
        nz |= (fabsf(v.x) >= 0.25f) | (fabsf(v.y) >= 0.25f) |
              (fabsf(v.z) >= 0.25f) | (fabsf(v.w) >= 0.25f);
        if (tid < 32) {
            float4 u = wc4[tid + 256];
            nz |= (fabsf(u.x) >= 0.25f) | (fabsf(u.y) >= 0.25f) |
                  (fabsf(u.z) >= 0.25f) | (fabsf(u.w) >= 0.25f);
        }
        // rintf(clip(w)*2) != 0  <=>  |w| >= 0.25 (round-half-even: 0.25 -> 0.5*... 
        // rintf(0.5)=0 ties-to-even would give 0! boundary: q = rintf(c*2)/2;
        // c*2 = 0.5 exactly -> rintf(0.5) = 0 (ties to even). So nonzero iff
        // c*2 > 0.5 strictly, i.e. |w| > 0.25. Using >= is CONSERVATIVE (may
        // take the slow exact path spuriously at |w|==0.25; never misses one).
        if (nz) s_flag = 1;               // benign LDS race, all write 1
    }
    __syncthreads();

    const float sc = s_scale;
    const float sh = s_shift;
    float4* out4 = (float4*)(out + (((size_t)b << 8) + co) * 3136);

    if (s_flag == 0) {
        // conv output is exactly 0.0f everywhere in this plane
        float y = __fadd_rn(__fmul_rn(0.0f, sc), sh);
        y = fminf(fmaxf(y, -1.0f), 1.0f);
        float qv = rintf(y * 2.0f) * 0.5f;
        float4 o = {qv, qv, qv, qv};
        out4[tid]       = o;               // 784 = 3*256 + 16
        out4[tid + 256] = o;
        out4[tid + 512] = o;
        if (tid < 16) out4[tid + 768] = o;
        return;
    }

    // ---- rare path: build exact nonzero list, then sparse conv ----
    if (tid == 0) s_cnt = 0;
    __syncthreads();
    const float* wc = w + co * 1152;
    for (int j = tid; j < 1152; j += 256) {
        float wv = wc[j];
        float c  = fminf(fmaxf(wv, -1.0f), 1.0f);
        float q  = rintf(c * 2.0f) * 0.5f;             // exact pow2 scaling
        if (q != 0.0f) {
            int slot = atomicAdd(&s_cnt, 1);
            s_idx[slot] = j;
            s_q[slot]   = q;
        }
    }
    __syncthreads();
    const int cnt = s_cnt;

    const float* xb = x + (size_t)b * 128 * 3136;
    for (int i = tid; i < 784; i += 256) {
        int flat = i * 4;                  // 56 % 4 == 0: 4 positions, one h row
        int h  = flat / 56;
        int w0 = flat - h * 56;

        float acc0 = 0.0f, acc1 = 0.0f, acc2 = 0.0f, acc3 = 0.0f;
        for (int e = 0; e < cnt; ++e) {
            int   idx = s_idx[e];
            float q   = s_q[e];
            int ci = idx / 9;
            int r9 = idx - ci * 9;
            int kh = r9 / 3;
            int kw = r9 - kh * 3;
            int hh = h + kh - 1;
            if (hh < 0 || hh >= 56) continue;
            const float* xrow = xb + (ci * 56 + hh) * 56;
            int wb = w0 + kw - 1;              // in [-1, 53]
            if (wb >= 0)      acc0 += q * xrow[wb];
            /* wb+1 in [0,54] */ acc1 += q * xrow[wb + 1];
            if (wb + 2 < 56)  acc2 += q * xrow[wb + 2];
            if (wb + 3 < 56)  acc3 += q * xrow[wb + 3];
        }

        float4 o;
        {
            float y = __fadd_rn(__fmul_rn(acc0, sc), sh);
            y = fminf(fmaxf(y, -1.0f), 1.0f);
            o.x = rintf(y * 2.0f) * 0.5f;
        }
        {
            float y = __fadd_rn(__fmul_rn(acc1, sc), sh);
            y = fminf(fmaxf(y, -1.0f), 1.0f);
            o.y = rintf(y * 2.0f) * 0.5f;
        }
        {
            float y = __fadd_rn(__fmul_rn(acc2, sc), sh);
            y = fminf(fmaxf(y, -1.0f), 1.0f);
            o.z = rintf(y * 2.0f) * 0.5f;
        }
        {
            float y = __fadd_rn(__fmul_rn(acc3, sc), sh);
            y = fminf(fmaxf(y, -1.0f), 1.0f);
            o.w = rintf(y * 2.0f) * 0.5f;
        }
        out4[i] = o;
    }
}

extern "C" void kernel_launch(void* const* d_in, const int* in_sizes, int n_in,
                              void* d_out, int out_size, void* d_ws, size_t ws_size,
                              hipStream_t stream) {
    const float* x     = (const float*)d_in[0];
    const float* w     = (const float*)d_in[1];
    const float* gamma = (const float*)d_in[2];
    const float* beta  = (const float*)d_in[3];
    const float* rmean = (const float*)d_in[4];
    const float* rvar  = (const float*)d_in[5];
    float* out = (float*)d_out;

    // one block per (b, co) output plane: 64 * 256 = 16384 blocks
    fused_all<<<16384, 256, 0, stream>>>(x, w, gamma, beta, rmean, rvar, out);
}